// Round 1
// baseline (8994.219 us; speedup 1.0000x reference)
//
#include <hip/hip_runtime.h>
#include <hip/hip_bf16.h>

// Problem dims (B=1)
#define L_SEQ 2048
#define NH    24
#define DH    128
#define HID   3072          // NH*DH
#define MLPD  12288         // 4*HID
#define N1    21504         // 3*HID + MLP
#define K2    15360         // HID + MLP
#define EPSF  1e-6f

__device__ __forceinline__ float gelu_tanh(float x) {
    float x3 = x * x * x;
    return 0.5f * x * (1.f + tanhf(0.7978845608028654f * (x + 0.044715f * x3)));
}

// ---------------- mod = silu(vec) @ mod_w + mod_b  (split-K + atomics) -----
__global__ __launch_bounds__(256)
void k_mod(const float* __restrict__ vec, const float* __restrict__ mod_w,
           const float* __restrict__ mod_b, float* __restrict__ mod) {
    __shared__ float sv[384];
    const int j  = blockIdx.x * 256 + threadIdx.x;   // 0..9215
    const int k0 = blockIdx.y * 384;
    for (int i = threadIdx.x; i < 384; i += 256) {
        float v = vec[k0 + i];
        sv[i] = v / (1.f + __expf(-v));
    }
    __syncthreads();
    float acc = (blockIdx.y == 0) ? mod_b[j] : 0.f;
    #pragma unroll 8
    for (int i = 0; i < 384; i++)
        acc = fmaf(sv[i], mod_w[(size_t)(k0 + i) * 9216 + j], acc);
    atomicAdd(&mod[j], acc);
}

// ---------------- LayerNorm + modulate ------------------------------------
__global__ __launch_bounds__(256)
void k_ln(const float* __restrict__ x, const float* __restrict__ mod,
          const float* __restrict__ gamma, const float* __restrict__ beta,
          float* __restrict__ x_mod) {
    __shared__ float rs_[4], rs2_[4];
    const int l = blockIdx.x, tid = threadIdx.x;
    const float* xr = x + (size_t)l * HID;
    float s = 0.f, s2 = 0.f;
    for (int i = tid; i < HID; i += 256) {
        float v = xr[i]; s += v; s2 = fmaf(v, v, s2);
    }
    #pragma unroll
    for (int off = 32; off; off >>= 1) { s += __shfl_xor(s, off); s2 += __shfl_xor(s2, off); }
    const int w = tid >> 6;
    if ((tid & 63) == 0) { rs_[w] = s; rs2_[w] = s2; }
    __syncthreads();
    s  = rs_[0] + rs_[1] + rs_[2] + rs_[3];
    s2 = rs2_[0] + rs2_[1] + rs2_[2] + rs2_[3];
    float mu   = s * (1.f / HID);
    float var  = s2 * (1.f / HID) - mu * mu;
    float rstd = rsqrtf(var + EPSF);
    float* orow = x_mod + (size_t)l * HID;
    for (int i = tid; i < HID; i += 256) {
        float ln = (xr[i] - mu) * rstd * gamma[i] + beta[i];
        orow[i] = fmaf(1.f + mod[HID + i], ln, mod[i]);
    }
}

// ---------------- tiled fp32 GEMM, 128x128x16, 8x8 per thread -------------
// MODE 0: A(x_mod 2048xHID) @ w1 -> scatter qkv [3][NH][L][DH] + gelu(mlp)
// MODE 1: A(concat attn|mlp) @ w2 -> out = x + gate*val
template<int MODE>
__global__ __launch_bounds__(256)
void gemm_k(const float* __restrict__ A, const float* __restrict__ A2,
            const float* __restrict__ B, const float* __restrict__ bias,
            int M, int N, int K,
            float* __restrict__ o0, float* __restrict__ o1,
            const float* __restrict__ xres, const float* __restrict__ mod) {
    __shared__ float As[16][132];
    __shared__ float Bs[16][128];
    const int tid = threadIdx.x;
    const int bm = blockIdx.y * 128;
    const int bn = blockIdx.x * 128;
    const int tx = tid & 15, ty = tid >> 4;
    const int lak = tid & 15, lar = tid >> 4;
    const int lbc = tid & 127, lbk = tid >> 7;
    float acc[8][8];
    #pragma unroll
    for (int i = 0; i < 8; i++)
        #pragma unroll
        for (int j = 0; j < 8; j++) acc[i][j] = 0.f;

    for (int k0 = 0; k0 < K; k0 += 16) {
        if (MODE == 0) {
            #pragma unroll
            for (int i = 0; i < 8; i++)
                As[lak][lar + 16 * i] = A[(size_t)(bm + lar + 16 * i) * K + (k0 + lak)];
        } else {
            if (k0 < HID) {
                #pragma unroll
                for (int i = 0; i < 8; i++)
                    As[lak][lar + 16 * i] = A[(size_t)(bm + lar + 16 * i) * HID + (k0 + lak)];
            } else {
                #pragma unroll
                for (int i = 0; i < 8; i++)
                    As[lak][lar + 16 * i] = A2[(size_t)(bm + lar + 16 * i) * MLPD + (k0 + lak - HID)];
            }
        }
        #pragma unroll
        for (int i = 0; i < 8; i++)
            Bs[lbk + 2 * i][lbc] = B[(size_t)(k0 + lbk + 2 * i) * N + (bn + lbc)];
        __syncthreads();
        #pragma unroll
        for (int kk = 0; kk < 16; kk++) {
            float a[8], b[8];
            *(float4*)&a[0] = *(const float4*)&As[kk][ty * 8];
            *(float4*)&a[4] = *(const float4*)&As[kk][ty * 8 + 4];
            *(float4*)&b[0] = *(const float4*)&Bs[kk][tx * 8];
            *(float4*)&b[4] = *(const float4*)&Bs[kk][tx * 8 + 4];
            #pragma unroll
            for (int i = 0; i < 8; i++)
                #pragma unroll
                for (int j = 0; j < 8; j++)
                    acc[i][j] = fmaf(a[i], b[j], acc[i][j]);
        }
        __syncthreads();
    }
    #pragma unroll
    for (int i = 0; i < 8; i++) {
        const int row = bm + ty * 8 + i;
        #pragma unroll
        for (int j = 0; j < 8; j++) {
            const int col = bn + tx * 8 + j;
            float v = acc[i][j] + bias[col];
            if (MODE == 0) {
                if (col < 3 * HID) {
                    int s = col / HID;
                    int r = col - s * HID;
                    int hh = r >> 7, d = r & 127;
                    o0[(((size_t)s * NH + hh) * L_SEQ + row) * DH + d] = v;
                } else {
                    o1[(size_t)row * MLPD + (col - 3 * HID)] = gelu_tanh(v);
                }
            } else {
                o0[(size_t)row * HID + col] =
                    fmaf(mod[2 * HID + col], v, xres[(size_t)row * HID + col]);
            }
        }
    }
}

// ---------------- RMSNorm(q,k) + RoPE, in place ---------------------------
__global__ __launch_bounds__(64)
void k_rmsrope(float* __restrict__ qkv, const float* __restrict__ pe,
               const float* __restrict__ qsc, const float* __restrict__ ksc) {
    const int idx = blockIdx.x;            // h*L + l
    const int h = idx >> 11, l = idx & 2047;
    const int p = threadIdx.x;             // pair index 0..63
    float* qp = qkv + ((size_t)h * L_SEQ + l) * DH;
    float* kp = qkv + ((size_t)(NH + h) * L_SEQ + l) * DH;
    const float4 pv = *(const float4*)&pe[((size_t)l * 64 + p) * 4];
    const float2 qs2 = *(const float2*)&qsc[2 * p];
    const float2 ks2 = *(const float2*)&ksc[2 * p];

    float2 t = *(float2*)&qp[2 * p];
    float ss = fmaf(t.x, t.x, t.y * t.y);
    #pragma unroll
    for (int off = 32; off; off >>= 1) ss += __shfl_xor(ss, off);
    float r = rsqrtf(ss * (1.f / DH) + EPSF);
    float a = t.x * r * qs2.x, b = t.y * r * qs2.y;
    *(float2*)&qp[2 * p] = make_float2(fmaf(pv.x, a, pv.y * b), fmaf(pv.z, a, pv.w * b));

    t = *(float2*)&kp[2 * p];
    ss = fmaf(t.x, t.x, t.y * t.y);
    #pragma unroll
    for (int off = 32; off; off >>= 1) ss += __shfl_xor(ss, off);
    r = rsqrtf(ss * (1.f / DH) + EPSF);
    a = t.x * r * ks2.x; b = t.y * r * ks2.y;
    *(float2*)&kp[2 * p] = make_float2(fmaf(pv.x, a, pv.y * b), fmaf(pv.z, a, pv.w * b));
}

// ---------------- flash attention (fp32, online softmax) ------------------
// block: 256 threads = 4 waves; 8 queries/block; 32-key tiles.
// lane -> (qi = lane>>5, kj = lane&31); query qq = 2*wave + qi.
__global__ __launch_bounds__(256)
void attn_k(const float* __restrict__ qkv, float* __restrict__ attn_out) {
    __shared__ float Ks[32][132];
    __shared__ float Vs[32][128];
    __shared__ float Qs[8][128];
    __shared__ float Ps[8][32];
    const int h = blockIdx.y;
    const int q0 = blockIdx.x * 8;
    const int tid = threadIdx.x;
    const int w = tid >> 6, lane = tid & 63;
    const int qi = lane >> 5, kj = lane & 31;
    const int qq = w * 2 + qi;
    const float* Qp = qkv + (size_t)h * (L_SEQ * DH);
    const float* Kp = qkv + (size_t)(NH + h) * (L_SEQ * DH);
    const float* Vp = qkv + (size_t)(2 * NH + h) * (L_SEQ * DH);
    {
        int r = tid >> 5, c4 = (tid & 31) * 4;
        *(float4*)&Qs[r][c4] = *(const float4*)&Qp[(size_t)(q0 + r) * DH + c4];
    }
    float m = -1e30f, lsum = 0.f;
    float o0 = 0.f, o1 = 0.f, o2 = 0.f, o3 = 0.f;

    for (int kt = 0; kt < L_SEQ; kt += 32) {
        __syncthreads();
        #pragma unroll
        for (int it = 0; it < 4; it++) {
            int idx = tid + it * 256;               // 0..1023
            int r = idx >> 5, c4 = (idx & 31) * 4;
            *(float4*)&Ks[r][c4] = *(const float4*)&Kp[(size_t)(kt + r) * DH + c4];
            *(float4*)&Vs[r][c4] = *(const float4*)&Vp[(size_t)(kt + r) * DH + c4];
        }
        __syncthreads();
        // score: dot(Q[qq], K[kj]) with 4 independent chains
        float sa = 0.f, sb = 0.f, sc = 0.f, sd = 0.f;
        #pragma unroll 8
        for (int g = 0; g < 32; g++) {
            float4 qv = *(const float4*)&Qs[qq][g * 4];
            float4 kv = *(const float4*)&Ks[kj][g * 4];
            sa = fmaf(qv.x, kv.x, sa); sb = fmaf(qv.y, kv.y, sb);
            sc = fmaf(qv.z, kv.z, sc); sd = fmaf(qv.w, kv.w, sd);
        }
        float s = ((sa + sb) + (sc + sd)) * 0.08838834764831845f;
        float tmax = s;
        #pragma unroll
        for (int off = 16; off; off >>= 1) tmax = fmaxf(tmax, __shfl_xor(tmax, off));
        float mn = fmaxf(m, tmax);
        float p = __expf(s - mn);
        float ps = p;
        #pragma unroll
        for (int off = 16; off; off >>= 1) ps += __shfl_xor(ps, off);
        float alpha = __expf(m - mn);
        lsum = fmaf(lsum, alpha, ps);
        m = mn;
        o0 *= alpha; o1 *= alpha; o2 *= alpha; o3 *= alpha;
        Ps[qq][kj] = p;
        __syncthreads();
        #pragma unroll 8
        for (int key = 0; key < 32; key++) {
            float pvv = Ps[qq][key];
            float4 vv = *(const float4*)&Vs[key][kj * 4];
            o0 = fmaf(pvv, vv.x, o0); o1 = fmaf(pvv, vv.y, o1);
            o2 = fmaf(pvv, vv.z, o2); o3 = fmaf(pvv, vv.w, o3);
        }
    }
    float inv = 1.f / lsum;
    *(float4*)&attn_out[(size_t)(q0 + qq) * HID + h * DH + kj * 4] =
        make_float4(o0 * inv, o1 * inv, o2 * inv, o3 * inv);
}

// ---------------------------------------------------------------------------
extern "C" void kernel_launch(void* const* d_in, const int* in_sizes, int n_in,
                              void* d_out, int out_size, void* d_ws, size_t ws_size,
                              hipStream_t stream) {
    (void)in_sizes; (void)n_in; (void)out_size; (void)ws_size;
    const float* x      = (const float*)d_in[0];
    const float* vec    = (const float*)d_in[1];
    const float* pe     = (const float*)d_in[2];
    const float* mod_w  = (const float*)d_in[3];
    const float* mod_b  = (const float*)d_in[4];
    const float* gamma  = (const float*)d_in[5];
    const float* beta   = (const float*)d_in[6];
    const float* w1     = (const float*)d_in[7];
    const float* b1     = (const float*)d_in[8];
    const float* q_s    = (const float*)d_in[9];
    const float* k_s    = (const float*)d_in[10];
    const float* w2     = (const float*)d_in[11];
    const float* b2     = (const float*)d_in[12];
    float* out = (float*)d_out;

    float* ws = (float*)d_ws;
    float* mod   = ws;                                   // 9216
    float* x_mod = ws + 16384;                           // L*HID  (reused as attn_out)
    float* qkv   = x_mod + (size_t)L_SEQ * HID;          // 3*NH*L*DH
    float* mlp   = qkv + (size_t)3 * NH * L_SEQ * DH;    // L*MLPD
    float* attn_out = x_mod;                             // alias: x_mod dead after GEMM1

    hipMemsetAsync(mod, 0, 9216 * sizeof(float), stream);

    k_mod<<<dim3(36, 8), 256, 0, stream>>>(vec, mod_w, mod_b, mod);
    k_ln<<<L_SEQ, 256, 0, stream>>>(x, mod, gamma, beta, x_mod);
    gemm_k<0><<<dim3(N1 / 128, L_SEQ / 128), 256, 0, stream>>>(
        x_mod, nullptr, w1, b1, L_SEQ, N1, HID, qkv, mlp, nullptr, nullptr);
    k_rmsrope<<<NH * L_SEQ, 64, 0, stream>>>(qkv, pe, q_s, k_s);
    attn_k<<<dim3(L_SEQ / 8, NH), 256, 0, stream>>>(qkv, attn_out);
    gemm_k<1><<<dim3(HID / 128, L_SEQ / 128), 256, 0, stream>>>(
        attn_out, mlp, w2, b2, L_SEQ, HID, K2, out, nullptr, x, mod);
}

// Round 2
// 3216.508 us; speedup vs baseline: 2.7963x; 2.7963x over previous
//
#include <hip/hip_runtime.h>
#include <hip/hip_bf16.h>
#include <cstdint>

// Problem dims (B=1)
#define L_SEQ 2048
#define NH    24
#define DH    128
#define HID   3072          // NH*DH
#define MLPD  12288         // 4*HID
#define N1    21504         // 3*HID + MLP
#define K2    15360         // HID + MLP
#define EPSF  1e-6f

typedef __bf16 bf16x8 __attribute__((ext_vector_type(8)));
typedef float  f32x4  __attribute__((ext_vector_type(4)));

__device__ __forceinline__ float gelu_tanh(float x) {
    float x3 = x * x * x;
    return 0.5f * x * (1.f + tanhf(0.7978845608028654f * (x + 0.044715f * x3)));
}

// float -> bf16 bits, round-to-nearest-even (finite inputs)
__device__ __forceinline__ unsigned short f2bf(float f) {
    union { float f; unsigned int u; } x{f};
    unsigned int r = x.u + 0x7fffu + ((x.u >> 16) & 1u);
    return (unsigned short)(r >> 16);
}

// async global->LDS, 16B per lane; LDS dest is wave-uniform base + lane*16
__device__ __forceinline__ void gload_lds16(const void* g, void* l) {
    __builtin_amdgcn_global_load_lds(
        (__attribute__((address_space(1))) void*)g,
        (__attribute__((address_space(3))) void*)l, 16, 0, 0);
}

// ---------------- fp32 [R][C] -> bf16 [C][R] tile transpose ---------------
__global__ __launch_bounds__(256)
void k_convT(const float* __restrict__ in, unsigned short* __restrict__ out,
             int R, int C) {
    __shared__ unsigned short s[64][72];
    const int r0 = blockIdx.y * 64, c0 = blockIdx.x * 64;
    const int tid = threadIdx.x;
    const int row = tid >> 4, c4 = (tid & 15) * 4;
    #pragma unroll
    for (int rr = 0; rr < 4; rr++) {
        int r = row + rr * 16;
        float4 v = *(const float4*)&in[(size_t)(r0 + r) * C + c0 + c4];
        s[r][c4 + 0] = f2bf(v.x); s[r][c4 + 1] = f2bf(v.y);
        s[r][c4 + 2] = f2bf(v.z); s[r][c4 + 3] = f2bf(v.w);
    }
    __syncthreads();
    #pragma unroll
    for (int rr = 0; rr < 4; rr++) {
        int oc = row + rr * 16;          // tile-col index (out row)
        ushort4 t = make_ushort4(s[c4 + 0][oc], s[c4 + 1][oc],
                                 s[c4 + 2][oc], s[c4 + 3][oc]);
        *(ushort4*)&out[(size_t)(c0 + oc) * R + r0 + c4] = t;
    }
}

// ---------------- mod = silu(vec) @ mod_w + mod_b  (split-K + atomics) -----
__global__ __launch_bounds__(256)
void k_mod(const float* __restrict__ vec, const float* __restrict__ mod_w,
           const float* __restrict__ mod_b, float* __restrict__ mod) {
    __shared__ float sv[384];
    const int j  = blockIdx.x * 256 + threadIdx.x;   // 0..9215
    const int k0 = blockIdx.y * 384;
    for (int i = threadIdx.x; i < 384; i += 256) {
        float v = vec[k0 + i];
        sv[i] = v / (1.f + __expf(-v));
    }
    __syncthreads();
    float acc = (blockIdx.y == 0) ? mod_b[j] : 0.f;
    #pragma unroll 8
    for (int i = 0; i < 384; i++)
        acc = fmaf(sv[i], mod_w[(size_t)(k0 + i) * 9216 + j], acc);
    atomicAdd(&mod[j], acc);
}

// ---------------- LayerNorm + modulate -> bf16 ----------------------------
__global__ __launch_bounds__(256)
void k_ln(const float* __restrict__ x, const float* __restrict__ mod,
          const float* __restrict__ gamma, const float* __restrict__ beta,
          unsigned short* __restrict__ x_mod) {
    __shared__ float rs_[4], rs2_[4];
    const int l = blockIdx.x, tid = threadIdx.x;
    const float* xr = x + (size_t)l * HID;
    float s = 0.f, s2 = 0.f;
    for (int i = tid; i < HID; i += 256) {
        float v = xr[i]; s += v; s2 = fmaf(v, v, s2);
    }
    #pragma unroll
    for (int off = 32; off; off >>= 1) { s += __shfl_xor(s, off); s2 += __shfl_xor(s2, off); }
    const int w = tid >> 6;
    if ((tid & 63) == 0) { rs_[w] = s; rs2_[w] = s2; }
    __syncthreads();
    s  = rs_[0] + rs_[1] + rs_[2] + rs_[3];
    s2 = rs2_[0] + rs2_[1] + rs2_[2] + rs2_[3];
    float mu   = s * (1.f / HID);
    float var  = s2 * (1.f / HID) - mu * mu;
    float rstd = rsqrtf(var + EPSF);
    unsigned short* orow = x_mod + (size_t)l * HID;
    for (int i = tid; i < HID; i += 256) {
        float ln = (xr[i] - mu) * rstd * gamma[i] + beta[i];
        orow[i] = f2bf(fmaf(1.f + mod[HID + i], ln, mod[i]));
    }
}

// ---------------- bf16 MFMA GEMM (B^T input), 128x128x32 ------------------
// MODE 0: x_mod[2048][3072] @ w1t^T -> qkv scatter (fp32) + gelu(mlp)->a2 bf16
// MODE 1: a2[2048][15360] @ w2t^T  -> out = x + gate*val (fp32)
template<int MODE>
__global__ __launch_bounds__(256)
void gemm_bt(const unsigned short* __restrict__ A,
             const unsigned short* __restrict__ Bt,
             const float* __restrict__ bias, int K,
             float* __restrict__ qkv, unsigned short* __restrict__ a2,
             const float* __restrict__ xres, const float* __restrict__ mod,
             float* __restrict__ out) {
    __shared__ unsigned short As[128 * 32];
    __shared__ unsigned short Bs[128 * 32];
    const int tid = threadIdx.x;
    const int bm = blockIdx.y * 128, bn = blockIdx.x * 128;
    const int w = tid >> 6, lane = tid & 63;
    const int wm = w >> 1, wn = w & 1;
    const int quad = lane >> 4, lr = lane & 15;
    const int srow = lane >> 2, spart = lane & 3;   // staging: 4 lanes/row x 16B

    f32x4 acc[4][4] = {};

    for (int k0 = 0; k0 < K; k0 += 32) {
        #pragma unroll
        for (int s = 0; s < 2; s++) {
            const int slot = w + s * 4;             // 16 rows per slot
            gload_lds16(&A [(size_t)(bm + slot * 16 + srow) * K + k0 + spart * 8],
                        &As[slot * 512]);
            gload_lds16(&Bt[(size_t)(bn + slot * 16 + srow) * K + k0 + spart * 8],
                        &Bs[slot * 512]);
        }
        __syncthreads();
        bf16x8 af[4], bfr[4];
        #pragma unroll
        for (int t = 0; t < 4; t++) {
            af[t]  = *(const bf16x8*)&As[(wm * 64 + t * 16 + lr) * 32 + quad * 8];
            bfr[t] = *(const bf16x8*)&Bs[(wn * 64 + t * 16 + lr) * 32 + quad * 8];
        }
        #pragma unroll
        for (int mt = 0; mt < 4; mt++)
            #pragma unroll
            for (int nt = 0; nt < 4; nt++)
                acc[mt][nt] = __builtin_amdgcn_mfma_f32_16x16x32_bf16(
                    af[mt], bfr[nt], acc[mt][nt], 0, 0, 0);
        __syncthreads();
    }

    #pragma unroll
    for (int mt = 0; mt < 4; mt++) {
        #pragma unroll
        for (int nt = 0; nt < 4; nt++) {
            const int col = bn + wn * 64 + nt * 16 + lr;
            const float bs = bias[col];
            #pragma unroll
            for (int r = 0; r < 4; r++) {
                const int row = bm + wm * 64 + mt * 16 + quad * 4 + r;
                float v = acc[mt][nt][r] + bs;
                if (MODE == 0) {
                    if (col < 3 * HID) {
                        int s3 = col / HID, rem = col - s3 * HID;
                        int hh = rem >> 7, d = rem & 127;
                        qkv[(((size_t)s3 * NH + hh) * L_SEQ + row) * DH + d] = v;
                    } else {
                        a2[(size_t)row * K2 + col - 6144] = f2bf(gelu_tanh(v));
                    }
                } else {
                    out[(size_t)row * HID + col] =
                        fmaf(mod[2 * HID + col], v, xres[(size_t)row * HID + col]);
                }
            }
        }
    }
}

// ---------------- RMSNorm(q,k) + RoPE, in place (fp32) --------------------
__global__ __launch_bounds__(64)
void k_rmsrope(float* __restrict__ qkv, const float* __restrict__ pe,
               const float* __restrict__ qsc, const float* __restrict__ ksc) {
    const int idx = blockIdx.x;            // h*L + l
    const int h = idx >> 11, l = idx & 2047;
    const int p = threadIdx.x;             // pair index 0..63
    float* qp = qkv + ((size_t)h * L_SEQ + l) * DH;
    float* kp = qkv + ((size_t)(NH + h) * L_SEQ + l) * DH;
    const float4 pv = *(const float4*)&pe[((size_t)l * 64 + p) * 4];
    const float2 qs2 = *(const float2*)&qsc[2 * p];
    const float2 ks2 = *(const float2*)&ksc[2 * p];

    float2 t = *(float2*)&qp[2 * p];
    float ss = fmaf(t.x, t.x, t.y * t.y);
    #pragma unroll
    for (int off = 32; off; off >>= 1) ss += __shfl_xor(ss, off);
    float r = rsqrtf(ss * (1.f / DH) + EPSF);
    float a = t.x * r * qs2.x, b = t.y * r * qs2.y;
    *(float2*)&qp[2 * p] = make_float2(fmaf(pv.x, a, pv.y * b), fmaf(pv.z, a, pv.w * b));

    t = *(float2*)&kp[2 * p];
    ss = fmaf(t.x, t.x, t.y * t.y);
    #pragma unroll
    for (int off = 32; off; off >>= 1) ss += __shfl_xor(ss, off);
    r = rsqrtf(ss * (1.f / DH) + EPSF);
    a = t.x * r * ks2.x; b = t.y * r * ks2.y;
    *(float2*)&kp[2 * p] = make_float2(fmaf(pv.x, a, pv.y * b), fmaf(pv.z, a, pv.w * b));
}

// ---------------- flash attention (fp32, online softmax) -> bf16 out ------
__global__ __launch_bounds__(256)
void attn_k(const float* __restrict__ qkv, unsigned short* __restrict__ a2) {
    __shared__ float Ks[32][132];
    __shared__ float Vs[32][128];
    __shared__ float Qs[8][128];
    __shared__ float Ps[8][32];
    const int h = blockIdx.y;
    const int q0 = blockIdx.x * 8;
    const int tid = threadIdx.x;
    const int w = tid >> 6, lane = tid & 63;
    const int qi = lane >> 5, kj = lane & 31;
    const int qq = w * 2 + qi;
    const float* Qp = qkv + (size_t)h * (L_SEQ * DH);
    const float* Kp = qkv + (size_t)(NH + h) * (L_SEQ * DH);
    const float* Vp = qkv + (size_t)(2 * NH + h) * (L_SEQ * DH);
    {
        int r = tid >> 5, c4 = (tid & 31) * 4;
        *(float4*)&Qs[r][c4] = *(const float4*)&Qp[(size_t)(q0 + r) * DH + c4];
    }
    float m = -1e30f, lsum = 0.f;
    float o0 = 0.f, o1 = 0.f, o2 = 0.f, o3 = 0.f;

    for (int kt = 0; kt < L_SEQ; kt += 32) {
        __syncthreads();
        #pragma unroll
        for (int it = 0; it < 4; it++) {
            int idx = tid + it * 256;               // 0..1023
            int r = idx >> 5, c4 = (idx & 31) * 4;
            *(float4*)&Ks[r][c4] = *(const float4*)&Kp[(size_t)(kt + r) * DH + c4];
            *(float4*)&Vs[r][c4] = *(const float4*)&Vp[(size_t)(kt + r) * DH + c4];
        }
        __syncthreads();
        float sa = 0.f, sb = 0.f, sc = 0.f, sd = 0.f;
        #pragma unroll 8
        for (int g = 0; g < 32; g++) {
            float4 qv = *(const float4*)&Qs[qq][g * 4];
            float4 kv = *(const float4*)&Ks[kj][g * 4];
            sa = fmaf(qv.x, kv.x, sa); sb = fmaf(qv.y, kv.y, sb);
            sc = fmaf(qv.z, kv.z, sc); sd = fmaf(qv.w, kv.w, sd);
        }
        float s = ((sa + sb) + (sc + sd)) * 0.08838834764831845f;
        float tmax = s;
        #pragma unroll
        for (int off = 16; off; off >>= 1) tmax = fmaxf(tmax, __shfl_xor(tmax, off));
        float mn = fmaxf(m, tmax);
        float p = __expf(s - mn);
        float ps = p;
        #pragma unroll
        for (int off = 16; off; off >>= 1) ps += __shfl_xor(ps, off);
        float alpha = __expf(m - mn);
        lsum = fmaf(lsum, alpha, ps);
        m = mn;
        o0 *= alpha; o1 *= alpha; o2 *= alpha; o3 *= alpha;
        Ps[qq][kj] = p;
        __syncthreads();
        #pragma unroll 8
        for (int key = 0; key < 32; key++) {
            float pvv = Ps[qq][key];
            float4 vv = *(const float4*)&Vs[key][kj * 4];
            o0 = fmaf(pvv, vv.x, o0); o1 = fmaf(pvv, vv.y, o1);
            o2 = fmaf(pvv, vv.z, o2); o3 = fmaf(pvv, vv.w, o3);
        }
    }
    float inv = 1.f / lsum;
    *(ushort4*)&a2[(size_t)(q0 + qq) * K2 + h * DH + kj * 4] =
        make_ushort4(f2bf(o0 * inv), f2bf(o1 * inv), f2bf(o2 * inv), f2bf(o3 * inv));
}

// ---------------------------------------------------------------------------
extern "C" void kernel_launch(void* const* d_in, const int* in_sizes, int n_in,
                              void* d_out, int out_size, void* d_ws, size_t ws_size,
                              hipStream_t stream) {
    (void)in_sizes; (void)n_in; (void)out_size; (void)ws_size;
    const float* x      = (const float*)d_in[0];
    const float* vec    = (const float*)d_in[1];
    const float* pe     = (const float*)d_in[2];
    const float* mod_w  = (const float*)d_in[3];
    const float* mod_b  = (const float*)d_in[4];
    const float* gamma  = (const float*)d_in[5];
    const float* beta   = (const float*)d_in[6];
    const float* w1     = (const float*)d_in[7];
    const float* b1     = (const float*)d_in[8];
    const float* q_s    = (const float*)d_in[9];
    const float* k_s    = (const float*)d_in[10];
    const float* w2     = (const float*)d_in[11];
    const float* b2     = (const float*)d_in[12];
    float* out = (float*)d_out;

    char* ws = (char*)d_ws;
    size_t off = 0;
    float* modbuf = (float*)(ws + off);           off += 40960;
    unsigned short* x_mod = (unsigned short*)(ws + off); off += (size_t)L_SEQ * HID * 2;
    float* qkv = (float*)(ws + off);              off += (size_t)3 * NH * L_SEQ * DH * 4;
    unsigned short* a2  = (unsigned short*)(ws + off);   off += (size_t)L_SEQ * K2 * 2;
    unsigned short* w1t = (unsigned short*)(ws + off);   off += (size_t)N1 * HID * 2;
    unsigned short* w2t = (unsigned short*)(ws + off);   off += (size_t)HID * K2 * 2;

    // weight convert+transpose (bf16, [N][K])
    k_convT<<<dim3(N1 / 64, HID / 64), 256, 0, stream>>>(w1, w1t, HID, N1);
    k_convT<<<dim3(HID / 64, K2 / 64), 256, 0, stream>>>(w2, w2t, K2, HID);

    hipMemsetAsync(modbuf, 0, 9216 * sizeof(float), stream);
    k_mod<<<dim3(36, 8), 256, 0, stream>>>(vec, mod_w, mod_b, modbuf);
    k_ln<<<L_SEQ, 256, 0, stream>>>(x, modbuf, gamma, beta, x_mod);

    gemm_bt<0><<<dim3(N1 / 128, L_SEQ / 128), 256, 0, stream>>>(
        x_mod, w1t, b1, HID, qkv, a2, nullptr, nullptr, nullptr);

    k_rmsrope<<<NH * L_SEQ, 64, 0, stream>>>(qkv, pe, q_s, k_s);
    attn_k<<<dim3(L_SEQ / 8, NH), 256, 0, stream>>>(qkv, a2);

    gemm_bt<1><<<dim3(HID / 128, L_SEQ / 128), 256, 0, stream>>>(
        a2, w2t, b2, K2, nullptr, nullptr, x, modbuf, out);
}